// Round 1
// baseline (3075.254 us; speedup 1.0000x reference)
//
#include <hip/hip_runtime.h>
#include <stdint.h>

#define DIM 512
#define NCODE 8192
#define NTOK 16384                      // B*N = 4*4096
#define QELEMS (NTOK * DIM)             // 8388608
#define IDX_OFF QELEMS                  // indices start in d_out
#define LOSS_OFF (QELEMS + NTOK)        // loss scalar in d_out

// workspace layout (bytes)
//   imp   : float[NCODE*DIM]                      @ 0
//   norms : float[NCODE]                          @ NCODE*DIM*4
//   best  : u64[NTOK]                             @ WS_BEST_BYTE
//   loss  : float[1]                              @ WS_LOSS_BYTE
#define WS_BEST_BYTE ((size_t)(NCODE * DIM + NCODE) * 4)   // 16,809,984 (8-aligned)
#define WS_LOSS_BYTE (WS_BEST_BYTE + (size_t)NTOK * 8)

constexpr int BM = 128;   // block tile rows
constexpr int BN = 128;   // block tile cols
constexpr int BK = 16;    // K chunk
constexpr int KP = BK + 1; // LDS pad

// ---------------------------------------------------------------- init
__global__ void init_kernel(unsigned long long* __restrict__ best,
                            float* __restrict__ loss) {
    int i = blockIdx.x * blockDim.x + threadIdx.x;
    if (i < NTOK) best[i] = ~0ull;
    if (i == 0) *loss = 0.f;
}

// ------------------------------------------------- implicit = A @ B^T
// C[m,n] = sum_k A[m,k] * B[n,k]; A:[M,K], B:[N,K], C:[M,N], all row-major.
__global__ __launch_bounds__(256, 2)
void gemm_bt_kernel(const float* __restrict__ A, const float* __restrict__ B,
                    float* __restrict__ C, int M, int N, int K) {
    __shared__ float As[BM][KP];
    __shared__ float Bs[BN][KP];
    const int tid = threadIdx.x;
    const int tx = tid & 15;
    const int ty = tid >> 4;
    const int row0 = blockIdx.y * BM;
    const int col0 = blockIdx.x * BN;
    float acc[8][8] = {};

    for (int k0 = 0; k0 < K; k0 += BK) {
        #pragma unroll
        for (int s = tid; s < BM * (BK / 4); s += 256) {
            int r = s >> 2, c4 = (s & 3) << 2;
            const float4 v = *(const float4*)(A + (size_t)(row0 + r) * K + k0 + c4);
            As[r][c4] = v.x; As[r][c4 + 1] = v.y; As[r][c4 + 2] = v.z; As[r][c4 + 3] = v.w;
        }
        #pragma unroll
        for (int s = tid; s < BN * (BK / 4); s += 256) {
            int r = s >> 2, c4 = (s & 3) << 2;
            const float4 v = *(const float4*)(B + (size_t)(col0 + r) * K + k0 + c4);
            Bs[r][c4] = v.x; Bs[r][c4 + 1] = v.y; Bs[r][c4 + 2] = v.z; Bs[r][c4 + 3] = v.w;
        }
        __syncthreads();
        #pragma unroll
        for (int kk = 0; kk < BK; ++kk) {
            float a[8], b[8];
            #pragma unroll
            for (int i = 0; i < 8; ++i) a[i] = As[ty * 8 + i][kk];
            #pragma unroll
            for (int j = 0; j < 8; ++j) b[j] = Bs[tx * 8 + j][kk];
            #pragma unroll
            for (int i = 0; i < 8; ++i)
                #pragma unroll
                for (int j = 0; j < 8; ++j)
                    acc[i][j] = fmaf(a[i], b[j], acc[i][j]);
        }
        __syncthreads();
    }
    #pragma unroll
    for (int i = 0; i < 8; ++i) {
        float* cp = C + (size_t)(row0 + ty * 8 + i) * N + col0 + tx * 8;
        *(float4*)cp       = make_float4(acc[i][0], acc[i][1], acc[i][2], acc[i][3]);
        *(float4*)(cp + 4) = make_float4(acc[i][4], acc[i][5], acc[i][6], acc[i][7]);
    }
}

// -------------------------------------------------------- row norms^2
__global__ void norm_kernel(const float* __restrict__ Imp, float* __restrict__ norms) {
    int c = blockIdx.x;
    const float4 v = ((const float4*)(Imp + (size_t)c * DIM))[threadIdx.x];
    float s = v.x * v.x + v.y * v.y + v.z * v.z + v.w * v.w;
    #pragma unroll
    for (int o = 32; o > 0; o >>= 1) s += __shfl_down(s, o, 64);
    __shared__ float tmp[2];
    if ((threadIdx.x & 63) == 0) tmp[threadIdx.x >> 6] = s;
    __syncthreads();
    if (threadIdx.x == 0) norms[c] = tmp[0] + tmp[1];
}

// ---------------------------------------- distances + fused argmin
// d2[t,c] = norms[c] - 2 * dot(x_t, imp_c); atomicMin of packed (orderable, idx)
__global__ __launch_bounds__(256, 2)
void dist_kernel(const float* __restrict__ X, const float* __restrict__ Imp,
                 const float* __restrict__ norms,
                 unsigned long long* __restrict__ best) {
    __shared__ float As[BM][KP];
    __shared__ float Bs[BN][KP];
    __shared__ unsigned long long red[BM][16];
    const int tid = threadIdx.x;
    const int tx = tid & 15;
    const int ty = tid >> 4;
    const int row0 = blockIdx.y * BM;   // tokens
    const int col0 = blockIdx.x * BN;   // codes
    float acc[8][8] = {};

    for (int k0 = 0; k0 < DIM; k0 += BK) {
        #pragma unroll
        for (int s = tid; s < BM * (BK / 4); s += 256) {
            int r = s >> 2, c4 = (s & 3) << 2;
            const float4 v = *(const float4*)(X + (size_t)(row0 + r) * DIM + k0 + c4);
            As[r][c4] = v.x; As[r][c4 + 1] = v.y; As[r][c4 + 2] = v.z; As[r][c4 + 3] = v.w;
        }
        #pragma unroll
        for (int s = tid; s < BN * (BK / 4); s += 256) {
            int r = s >> 2, c4 = (s & 3) << 2;
            const float4 v = *(const float4*)(Imp + (size_t)(col0 + r) * DIM + k0 + c4);
            Bs[r][c4] = v.x; Bs[r][c4 + 1] = v.y; Bs[r][c4 + 2] = v.z; Bs[r][c4 + 3] = v.w;
        }
        __syncthreads();
        #pragma unroll
        for (int kk = 0; kk < BK; ++kk) {
            float a[8], b[8];
            #pragma unroll
            for (int i = 0; i < 8; ++i) a[i] = As[ty * 8 + i][kk];
            #pragma unroll
            for (int j = 0; j < 8; ++j) b[j] = Bs[tx * 8 + j][kk];
            #pragma unroll
            for (int i = 0; i < 8; ++i)
                #pragma unroll
                for (int j = 0; j < 8; ++j)
                    acc[i][j] = fmaf(a[i], b[j], acc[i][j]);
        }
        __syncthreads();
    }

    // epilogue: d2 = norms[c] - 2*acc, per-thread min, block reduce, atomicMin
    unsigned long long m[8];
    #pragma unroll
    for (int i = 0; i < 8; ++i) m[i] = ~0ull;
    #pragma unroll
    for (int j = 0; j < 8; ++j) {
        const int code = col0 + tx * 8 + j;
        const float nc = norms[code];
        #pragma unroll
        for (int i = 0; i < 8; ++i) {
            float d = fmaf(-2.f, acc[i][j], nc);
            unsigned u = __float_as_uint(d);
            u = (u & 0x80000000u) ? ~u : (u | 0x80000000u);
            unsigned long long p = ((unsigned long long)u << 32) | (unsigned)code;
            if (p < m[i]) m[i] = p;
        }
    }
    #pragma unroll
    for (int i = 0; i < 8; ++i) red[ty * 8 + i][tx] = m[i];
    __syncthreads();
    if (tid < BM) {
        unsigned long long mm = red[tid][0];
        #pragma unroll
        for (int t = 1; t < 16; ++t) {
            unsigned long long v = red[tid][t];
            if (v < mm) mm = v;
        }
        atomicMin(&best[row0 + tid], mm);
    }
}

// --------------------------------------- gather + indices + loss sum
__global__ void gather_kernel(const float* __restrict__ X, const float* __restrict__ Imp,
                              const unsigned long long* __restrict__ best,
                              float* __restrict__ out, float* __restrict__ loss) {
    const int t = blockIdx.x;
    const unsigned idx = (unsigned)(best[t] & 0xffffffffull);
    const float4 qv = ((const float4*)(Imp + (size_t)idx * DIM))[threadIdx.x];
    const float4 xv = ((const float4*)(X + (size_t)t * DIM))[threadIdx.x];
    ((float4*)(out + (size_t)t * DIM))[threadIdx.x] = qv;
    const float dx = xv.x - qv.x, dy = xv.y - qv.y, dz = xv.z - qv.z, dw = xv.w - qv.w;
    float s = dx * dx + dy * dy + dz * dz + dw * dw;
    #pragma unroll
    for (int o = 32; o > 0; o >>= 1) s += __shfl_down(s, o, 64);
    if ((threadIdx.x & 63) == 0) atomicAdd(loss, s);
    if (threadIdx.x == 0) out[IDX_OFF + t] = (float)idx;
}

// ------------------------------------------------------------ finalize
__global__ void fin_kernel(const float* __restrict__ loss, float* __restrict__ out) {
    out[LOSS_OFF] = 1.25f * (*loss) / (float)QELEMS;
}

extern "C" void kernel_launch(void* const* d_in, const int* in_sizes, int n_in,
                              void* d_out, int out_size, void* d_ws, size_t ws_size,
                              hipStream_t stream) {
    const float* x  = (const float*)d_in[0];   // [4,4096,512]
    const float* cb = (const float*)d_in[1];   // [8192,512]
    const float* W  = (const float*)d_in[2];   // [512,512]
    float* out = (float*)d_out;
    char* ws = (char*)d_ws;

    float* imp = (float*)ws;
    float* norms = imp + (size_t)NCODE * DIM;
    unsigned long long* best = (unsigned long long*)(ws + WS_BEST_BYTE);
    float* loss = (float*)(ws + WS_LOSS_BYTE);

    hipLaunchKernelGGL(init_kernel, dim3((NTOK + 255) / 256), dim3(256), 0, stream,
                       best, loss);
    // implicit = codebook @ W.T : M=NCODE, N=DIM, K=DIM
    hipLaunchKernelGGL(gemm_bt_kernel, dim3(DIM / BN, NCODE / BM), dim3(256), 0, stream,
                       cb, W, imp, NCODE, DIM, DIM);
    hipLaunchKernelGGL(norm_kernel, dim3(NCODE), dim3(128), 0, stream, imp, norms);
    hipLaunchKernelGGL(dist_kernel, dim3(NCODE / BN, NTOK / BM), dim3(256), 0, stream,
                       x, imp, norms, best);
    hipLaunchKernelGGL(gather_kernel, dim3(NTOK), dim3(128), 0, stream,
                       x, imp, best, out, loss);
    hipLaunchKernelGGL(fin_kernel, dim3(1), dim3(1), 0, stream, loss, out);
}

// Round 2
// 728.672 us; speedup vs baseline: 4.2204x; 4.2204x over previous
//
#include <hip/hip_runtime.h>
#include <stdint.h>

#define DIM 512
#define NCODE 8192
#define NTOK 16384                      // B*N = 4*4096
#define QELEMS (NTOK * DIM)             // 8388608
#define IDX_OFF QELEMS
#define LOSS_OFF (QELEMS + NTOK)

// ---------------- workspace layout (bytes) ----------------
// imp   fp32 [NCODE*DIM]   @ 0            (16 MB)
// norms fp32 [NCODE]       @ OFF_NORMS
// xbf   u16  [NTOK*DIM]    @ OFF_XBF      (16 MB)
// impbf u16  [NCODE*DIM]   @ OFF_IMPBF    (8 MB)
// cand  u32  [NTOK*64*4]   @ OFF_CAND     (16 MB)
// loss  f32  [1]           @ OFF_LOSS
#define OFF_NORMS ((size_t)NCODE * DIM * 4)
#define OFF_XBF   (OFF_NORMS + (size_t)NCODE * 4)
#define OFF_IMPBF (OFF_XBF + (size_t)NTOK * DIM * 2)
#define OFF_CAND  (OFF_IMPBF + (size_t)NCODE * DIM * 2)
#define OFF_LOSS  (OFF_CAND + (size_t)NTOK * 64 * 4 * 4)

typedef short bf16x8 __attribute__((ext_vector_type(8)));
typedef float f32x4 __attribute__((ext_vector_type(4)));

__device__ inline unsigned ord32(float f) {
    unsigned u = __float_as_uint(f);
    return (u & 0x80000000u) ? ~u : (u | 0x80000000u);
}
__device__ inline float unord32(unsigned u) {
    u = (u & 0x80000000u) ? (u & 0x7fffffffu) : ~u;
    return __uint_as_float(u);
}
__device__ inline unsigned short f2bf(float f) {  // RTN bf16
    unsigned u = __float_as_uint(f);
    return (unsigned short)((u + 0x7fffu + ((u >> 16) & 1u)) >> 16);
}
__device__ inline void gl_lds16(const void* g, void* l) {
    __builtin_amdgcn_global_load_lds(
        (const __attribute__((address_space(1))) void*)g,
        (__attribute__((address_space(3))) void*)l, 16, 0, 0);
}

// ---------------------------------------------------------------- init
__global__ void init_kernel(float* __restrict__ loss) {
    *loss = 0.f;
}

// ------------------------------------------------- implicit = cb @ W^T (fp32)
constexpr int BM = 128, BN = 128, BK = 16, KP = BK + 1;
__global__ __launch_bounds__(256, 2)
void gemm_bt_kernel(const float* __restrict__ A, const float* __restrict__ B,
                    float* __restrict__ C, int M, int N, int K) {
    __shared__ float As[BM][KP];
    __shared__ float Bs[BN][KP];
    const int tid = threadIdx.x;
    const int tx = tid & 15;
    const int ty = tid >> 4;
    const int row0 = blockIdx.y * BM;
    const int col0 = blockIdx.x * BN;
    float acc[8][8] = {};
    for (int k0 = 0; k0 < K; k0 += BK) {
        #pragma unroll
        for (int s = tid; s < BM * (BK / 4); s += 256) {
            int r = s >> 2, c4 = (s & 3) << 2;
            const float4 v = *(const float4*)(A + (size_t)(row0 + r) * K + k0 + c4);
            As[r][c4] = v.x; As[r][c4 + 1] = v.y; As[r][c4 + 2] = v.z; As[r][c4 + 3] = v.w;
        }
        #pragma unroll
        for (int s = tid; s < BN * (BK / 4); s += 256) {
            int r = s >> 2, c4 = (s & 3) << 2;
            const float4 v = *(const float4*)(B + (size_t)(col0 + r) * K + k0 + c4);
            Bs[r][c4] = v.x; Bs[r][c4 + 1] = v.y; Bs[r][c4 + 2] = v.z; Bs[r][c4 + 3] = v.w;
        }
        __syncthreads();
        #pragma unroll
        for (int kk = 0; kk < BK; ++kk) {
            float a[8], b[8];
            #pragma unroll
            for (int i = 0; i < 8; ++i) a[i] = As[ty * 8 + i][kk];
            #pragma unroll
            for (int j = 0; j < 8; ++j) b[j] = Bs[tx * 8 + j][kk];
            #pragma unroll
            for (int i = 0; i < 8; ++i)
                #pragma unroll
                for (int j = 0; j < 8; ++j)
                    acc[i][j] = fmaf(a[i], b[j], acc[i][j]);
        }
        __syncthreads();
    }
    #pragma unroll
    for (int i = 0; i < 8; ++i) {
        float* cp = C + (size_t)(row0 + ty * 8 + i) * N + col0 + tx * 8;
        *(float4*)cp       = make_float4(acc[i][0], acc[i][1], acc[i][2], acc[i][3]);
        *(float4*)(cp + 4) = make_float4(acc[i][4], acc[i][5], acc[i][6], acc[i][7]);
    }
}

// -------------------------------------------------------- row norms^2
__global__ void norm_kernel(const float* __restrict__ Imp, float* __restrict__ norms) {
    int c = blockIdx.x;
    const float4 v = ((const float4*)(Imp + (size_t)c * DIM))[threadIdx.x];
    float s = v.x * v.x + v.y * v.y + v.z * v.z + v.w * v.w;
    #pragma unroll
    for (int o = 32; o > 0; o >>= 1) s += __shfl_down(s, o, 64);
    __shared__ float tmp[2];
    if ((threadIdx.x & 63) == 0) tmp[threadIdx.x >> 6] = s;
    __syncthreads();
    if (threadIdx.x == 0) norms[c] = tmp[0] + tmp[1];
}

// -------------------------------------------------- fp32 -> bf16 convert
__global__ void cvt_kernel(const float* __restrict__ src,
                           unsigned short* __restrict__ dst, int n4) {
    int i = blockIdx.x * blockDim.x + threadIdx.x;
    if (i >= n4) return;
    float4 v = ((const float4*)src)[i];
    ushort4 o;
    o.x = f2bf(v.x); o.y = f2bf(v.y); o.z = f2bf(v.z); o.w = f2bf(v.w);
    ((ushort4*)dst)[i] = o;
}

// ------------------------------- coarse bf16 MFMA scoring + per-block top-4
// d2[t,c] = norms[c] - 2 * dot(x_t, imp_c)  (coarse, bf16 inputs, fp32 accum)
// writes cand[t][colblock][0..3] = (u16 orderable score << 16) | code  (sorted)
__global__ __launch_bounds__(256, 3)
void coarse_kernel(const unsigned short* __restrict__ Xbf,
                   const unsigned short* __restrict__ Ibf,
                   const float* __restrict__ norms,
                   unsigned* __restrict__ cand) {
    __shared__ __align__(16) unsigned short As[128 * 32];  // [row][k] k-major, NO pad
    __shared__ __align__(16) unsigned short Bs[128 * 32];
    __shared__ unsigned short S[128][130];                 // scores [token][code]

    const int tid = threadIdx.x;
    const int l = tid & 63;
    const int w = tid >> 6;
    const int row0 = blockIdx.y * 128;   // tokens
    const int col0 = blockIdx.x * 128;   // codes

    // staging: wave w loads rows [w*32, w*32+32) of A and B tiles, 2 issues each
    const int rr = l >> 2;               // 0..15 row within 16-row group
    const int seg = (l & 3) * 8;         // k-offset in shorts (16B chunks)
    const unsigned short* ga0 = Xbf + (size_t)(row0 + w * 32 + rr) * DIM + seg;
    const unsigned short* ga1 = ga0 + (size_t)16 * DIM;
    const unsigned short* gb0 = Ibf + (size_t)(col0 + w * 32 + rr) * DIM + seg;
    const unsigned short* gb1 = gb0 + (size_t)16 * DIM;
    unsigned short* la0 = As + (w * 32) * 32;       // wave-uniform LDS bases
    unsigned short* la1 = As + (w * 32 + 16) * 32;
    unsigned short* lb0 = Bs + (w * 32) * 32;
    unsigned short* lb1 = Bs + (w * 32 + 16) * 32;

    const int wm = w & 1, wn = w >> 1;   // wave sub-tile: 64x64
    const int lr = l & 15;
    const int kq = (l >> 4) * 8;         // k offset for fragment
    int aoff[4], boff[4];
    #pragma unroll
    for (int i = 0; i < 4; ++i) {
        aoff[i] = (wm * 64 + i * 16 + lr) * 32 + kq;
        boff[i] = (wn * 64 + i * 16 + lr) * 32 + kq;
    }

    f32x4 acc[4][4];
    #pragma unroll
    for (int i = 0; i < 4; ++i)
        #pragma unroll
        for (int j = 0; j < 4; ++j) acc[i][j] = (f32x4)0.f;

    for (int k0 = 0; k0 < DIM; k0 += 32) {
        gl_lds16(ga0, la0); gl_lds16(ga1, la1);
        gl_lds16(gb0, lb0); gl_lds16(gb1, lb1);
        ga0 += 32; ga1 += 32; gb0 += 32; gb1 += 32;
        __syncthreads();                 // drains vmcnt -> LDS tiles ready
        bf16x8 af[4], bfr[4];
        #pragma unroll
        for (int i = 0; i < 4; ++i) af[i] = *(const bf16x8*)(As + aoff[i]);
        #pragma unroll
        for (int i = 0; i < 4; ++i) bfr[i] = *(const bf16x8*)(Bs + boff[i]);
        #pragma unroll
        for (int i = 0; i < 4; ++i)
            #pragma unroll
            for (int j = 0; j < 4; ++j)
                acc[i][j] = __builtin_amdgcn_mfma_f32_16x16x32_bf16(
                    af[i], bfr[j], acc[i][j], 0, 0, 0);
        __syncthreads();                 // all reads done before next overwrite
    }

    // epilogue: d2 -> orderable u16 -> S[token][code]
    const int lrow = (l >> 4) * 4;
    #pragma unroll
    for (int j = 0; j < 4; ++j) {
        const int cloc = wn * 64 + j * 16 + lr;
        const float nc = norms[col0 + cloc];
        #pragma unroll
        for (int i = 0; i < 4; ++i) {
            #pragma unroll
            for (int r = 0; r < 4; ++r) {
                float d = fmaf(-2.f, acc[i][j][r], nc);
                S[wm * 64 + i * 16 + lrow + r][cloc] =
                    (unsigned short)(ord32(d) >> 16);
            }
        }
    }
    __syncthreads();

    // per-token top-4 scan (threads 0..127, one token each)
    if (tid < 128) {
        unsigned t0 = 0xffffffffu, t1 = 0xffffffffu, t2 = 0xffffffffu, t3 = 0xffffffffu;
        for (int c = 0; c < 128; ++c) {
            unsigned v = ((unsigned)S[tid][c] << 16) | (unsigned)(col0 + c);
            if (v < t3) {
                if (v < t2) {
                    t3 = t2;
                    if (v < t1) {
                        t2 = t1;
                        if (v < t0) { t1 = t0; t0 = v; } else t1 = v;
                    } else t2 = v;
                } else t3 = v;
            }
        }
        *(uint4*)(cand + ((size_t)(row0 + tid) * 64 + blockIdx.x) * 4) =
            make_uint4(t0, t1, t2, t3);
    }
}

// --------------- merge top-4 lists, exact fp32 rescore, gather, loss
__global__ __launch_bounds__(64)
void merge_kernel(const float* __restrict__ X, const float* __restrict__ Imp,
                  const float* __restrict__ norms, const unsigned* __restrict__ cand,
                  float* __restrict__ out, float* __restrict__ loss) {
    const int t = blockIdx.x;
    const int l = threadIdx.x;
    __shared__ int cnt;
    __shared__ unsigned short clist[64];
    if (l == 0) cnt = 0;

    const uint4 c4 = *(const uint4*)(cand + ((size_t)t * 64 + l) * 4);
    unsigned mn = min(min(c4.x, c4.y), min(c4.z, c4.w));
    #pragma unroll
    for (int o = 32; o > 0; o >>= 1)
        mn = min(mn, (unsigned)__shfl_xor((int)mn, o, 64));
    const float thresh = unord32(mn & 0xffff0000u) + 0.25f;  // coarse-err margin
    __syncthreads();

    unsigned vv[4] = {c4.x, c4.y, c4.z, c4.w};
    #pragma unroll
    for (int i = 0; i < 4; ++i) {
        if (unord32(vv[i] & 0xffff0000u) <= thresh) {
            int p = atomicAdd(&cnt, 1);
            if (p < 64) clist[p] = (unsigned short)(vv[i] & 0xffffu);
        }
    }
    __syncthreads();
    const int n = cnt < 64 ? cnt : 64;

    const float4* xp = (const float4*)(X + (size_t)t * DIM);
    const float4 xa = xp[l * 2], xb = xp[l * 2 + 1];
    unsigned long long best = ~0ull;
    for (int i = 0; i < n; ++i) {
        const int c = clist[i];
        const float4* ip = (const float4*)(Imp + (size_t)c * DIM);
        const float4 ia = ip[l * 2], ib = ip[l * 2 + 1];
        float s = xa.x * ia.x + xa.y * ia.y + xa.z * ia.z + xa.w * ia.w
                + xb.x * ib.x + xb.y * ib.y + xb.z * ib.z + xb.w * ib.w;
        #pragma unroll
        for (int o = 32; o > 0; o >>= 1) s += __shfl_xor(s, o, 64);
        const float d = fmaf(-2.f, s, norms[c]);
        const unsigned long long p = ((unsigned long long)ord32(d) << 32) | (unsigned)c;
        if (p < best) best = p;
    }
    const int bi = (int)(best & 0xffffffffu);

    // gather + commit loss
    const float4* qp = (const float4*)(Imp + (size_t)bi * DIM);
    float4* op = (float4*)(out + (size_t)t * DIM);
    float ls = 0.f;
    #pragma unroll
    for (int jj = 0; jj < 2; ++jj) {
        const int j = l + jj * 64;
        const float4 q = qp[j], xv = xp[j];
        op[j] = q;
        const float dx = xv.x - q.x, dy = xv.y - q.y, dz = xv.z - q.z, dw = xv.w - q.w;
        ls += dx * dx + dy * dy + dz * dz + dw * dw;
    }
    #pragma unroll
    for (int o = 32; o > 0; o >>= 1) ls += __shfl_xor(ls, o, 64);
    if (l == 0) {
        atomicAdd(loss, ls);
        out[IDX_OFF + t] = (float)bi;
    }
}

// ------------------------------------------------------------ finalize
__global__ void fin_kernel(const float* __restrict__ loss, float* __restrict__ out) {
    out[LOSS_OFF] = 1.25f * (*loss) / (float)QELEMS;
}

extern "C" void kernel_launch(void* const* d_in, const int* in_sizes, int n_in,
                              void* d_out, int out_size, void* d_ws, size_t ws_size,
                              hipStream_t stream) {
    const float* x  = (const float*)d_in[0];   // [4,4096,512]
    const float* cb = (const float*)d_in[1];   // [8192,512]
    const float* W  = (const float*)d_in[2];   // [512,512]
    float* out = (float*)d_out;
    char* ws = (char*)d_ws;

    float* imp = (float*)ws;
    float* norms = (float*)(ws + OFF_NORMS);
    unsigned short* xbf = (unsigned short*)(ws + OFF_XBF);
    unsigned short* impbf = (unsigned short*)(ws + OFF_IMPBF);
    unsigned* cand = (unsigned*)(ws + OFF_CAND);
    float* loss = (float*)(ws + OFF_LOSS);

    hipLaunchKernelGGL(init_kernel, dim3(1), dim3(1), 0, stream, loss);
    hipLaunchKernelGGL(gemm_bt_kernel, dim3(DIM / BN, NCODE / BM), dim3(256), 0, stream,
                       cb, W, imp, NCODE, DIM, DIM);
    hipLaunchKernelGGL(norm_kernel, dim3(NCODE), dim3(128), 0, stream, imp, norms);
    hipLaunchKernelGGL(cvt_kernel, dim3(NTOK * DIM / 4 / 256), dim3(256), 0, stream,
                       x, xbf, NTOK * DIM / 4);
    hipLaunchKernelGGL(cvt_kernel, dim3(NCODE * DIM / 4 / 256), dim3(256), 0, stream,
                       imp, impbf, NCODE * DIM / 4);
    hipLaunchKernelGGL(coarse_kernel, dim3(NCODE / 128, NTOK / 128), dim3(256), 0, stream,
                       xbf, impbf, norms, cand);
    hipLaunchKernelGGL(merge_kernel, dim3(NTOK), dim3(64), 0, stream,
                       x, imp, norms, cand, out, loss);
    hipLaunchKernelGGL(fin_kernel, dim3(1), dim3(1), 0, stream, loss, out);
}

// Round 3
// 595.101 us; speedup vs baseline: 5.1676x; 1.2245x over previous
//
#include <hip/hip_runtime.h>
#include <stdint.h>

#define DIM 512
#define NCODE 8192
#define NTOK 16384                      // B*N = 4*4096
#define QELEMS (NTOK * DIM)             // 8388608
#define IDX_OFF QELEMS
#define LOSS_OFF (QELEMS + NTOK)

// ---------------- workspace layout (bytes) ----------------
#define OFF_NORMS ((size_t)NCODE * DIM * 4)
#define OFF_XBF   (OFF_NORMS + (size_t)NCODE * 4)
#define OFF_IMPBF (OFF_XBF + (size_t)NTOK * DIM * 2)
#define OFF_CAND  (OFF_IMPBF + (size_t)NCODE * DIM * 2)
#define OFF_LOSS  (OFF_CAND + (size_t)NTOK * 64 * 4 * 4)

typedef short bf16x8 __attribute__((ext_vector_type(8)));
typedef float f32x4 __attribute__((ext_vector_type(4)));

__device__ inline unsigned ord32(float f) {
    unsigned u = __float_as_uint(f);
    return (u & 0x80000000u) ? ~u : (u | 0x80000000u);
}
__device__ inline float unord32(unsigned u) {
    u = (u & 0x80000000u) ? (u & 0x7fffffffu) : ~u;
    return __uint_as_float(u);
}
__device__ inline unsigned short f2bf(float f) {  // RTN bf16
    unsigned u = __float_as_uint(f);
    return (unsigned short)((u + 0x7fffu + ((u >> 16) & 1u)) >> 16);
}
__device__ inline void gl_lds16(const void* g, void* l) {
    __builtin_amdgcn_global_load_lds(
        (const __attribute__((address_space(1))) void*)g,
        (__attribute__((address_space(3))) void*)l, 16, 0, 0);
}

// ---------------------------------------------------------------- init
__global__ void init_kernel(float* __restrict__ loss, float* __restrict__ norms) {
    int i = blockIdx.x * blockDim.x + threadIdx.x;
    if (i < NCODE) norms[i] = 0.f;
    if (i == 0) *loss = 0.f;
}

// ---------------- implicit = cb @ W^T (fp32) + fused norms + bf16 copy
// M=NCODE, N=DIM(512), K=DIM(512). cols micro-tile tx + j*16 -> LDS stride 17
// across lanes (gcd(17,32)=1) -> conflict-free b-reads.
constexpr int BM = 128, BN = 128, BK = 16, KP = BK + 1;
__global__ __launch_bounds__(256, 2)
void gemm_bt_kernel(const float* __restrict__ A, const float* __restrict__ B,
                    float* __restrict__ C, unsigned short* __restrict__ Cbf,
                    float* __restrict__ norms) {
    __shared__ float As[BM][KP];
    __shared__ float Bs[BN][KP];
    const int tid = threadIdx.x;
    const int tx = tid & 15;
    const int ty = tid >> 4;
    const int row0 = blockIdx.y * BM;
    const int col0 = blockIdx.x * BN;
    float acc[8][8] = {};
    for (int k0 = 0; k0 < DIM; k0 += BK) {
        #pragma unroll
        for (int s = tid; s < BM * (BK / 4); s += 256) {
            int r = s >> 2, c4 = (s & 3) << 2;
            const float4 v = *(const float4*)(A + (size_t)(row0 + r) * DIM + k0 + c4);
            As[r][c4] = v.x; As[r][c4 + 1] = v.y; As[r][c4 + 2] = v.z; As[r][c4 + 3] = v.w;
        }
        #pragma unroll
        for (int s = tid; s < BN * (BK / 4); s += 256) {
            int r = s >> 2, c4 = (s & 3) << 2;
            const float4 v = *(const float4*)(B + (size_t)(col0 + r) * DIM + k0 + c4);
            Bs[r][c4] = v.x; Bs[r][c4 + 1] = v.y; Bs[r][c4 + 2] = v.z; Bs[r][c4 + 3] = v.w;
        }
        __syncthreads();
        #pragma unroll
        for (int kk = 0; kk < BK; ++kk) {
            float a[8], b[8];
            #pragma unroll
            for (int i = 0; i < 8; ++i) a[i] = As[ty * 8 + i][kk];       // broadcast
            #pragma unroll
            for (int j = 0; j < 8; ++j) b[j] = Bs[tx + j * 16][kk];      // conflict-free
            #pragma unroll
            for (int i = 0; i < 8; ++i)
                #pragma unroll
                for (int j = 0; j < 8; ++j)
                    acc[i][j] = fmaf(a[i], b[j], acc[i][j]);
        }
        __syncthreads();
    }
    #pragma unroll
    for (int i = 0; i < 8; ++i) {
        const int row = row0 + ty * 8 + i;
        float np = 0.f;
        #pragma unroll
        for (int j = 0; j < 8; ++j) {
            const int col = col0 + tx + j * 16;
            const float v = acc[i][j];
            C[(size_t)row * DIM + col] = v;
            Cbf[(size_t)row * DIM + col] = f2bf(v);
            np = fmaf(v, v, np);
        }
        #pragma unroll
        for (int m = 1; m < 16; m <<= 1) np += __shfl_xor(np, m, 64);
        if (tx == 0) atomicAdd(&norms[row], np);
    }
}

// -------------------------------------------------- fp32 -> bf16 convert (x)
__global__ void cvt_kernel(const float* __restrict__ src,
                           unsigned short* __restrict__ dst, int n4) {
    int i = blockIdx.x * blockDim.x + threadIdx.x;
    if (i >= n4) return;
    float4 v = ((const float4*)src)[i];
    ushort4 o;
    o.x = f2bf(v.x); o.y = f2bf(v.y); o.z = f2bf(v.z); o.w = f2bf(v.w);
    ((ushort4*)dst)[i] = o;
}

// ------------------------------- coarse bf16 MFMA scoring + per-block top-4
// d2[t,c] = norms[c] - 2 * dot(x_t, imp_c); per-token 4-smallest of 128 codes.
// LDS: S/red alias the As/Bs region (dead after K-loop) -> 36.5 KB -> 4 blk/CU.
__global__ __launch_bounds__(256, 4)
void coarse_kernel(const unsigned short* __restrict__ Xbf,
                   const unsigned short* __restrict__ Ibf,
                   const float* __restrict__ norms,
                   unsigned* __restrict__ cand) {
    __shared__ __align__(16) unsigned char smem[33280 + 4096];
    unsigned short* As = (unsigned short*)smem;            // [128][32]
    unsigned short* Bs = As + 128 * 32;                    // [128][32]
    unsigned short (*S)[130] = (unsigned short (*)[130])smem;  // aliases As/Bs
    unsigned* red = (unsigned*)(smem + 33280);             // [128][8]

    const int tid = threadIdx.x;
    const int l = tid & 63;
    const int w = tid >> 6;

    // XCD swizzle: same-XCD blocks share a small set of code tiles (L2-resident)
    const int id = blockIdx.y * 64 + blockIdx.x;
    const int xcd = id & 7;
    const int s8 = id >> 3;
    const int bx = xcd * 8 + (s8 & 7);
    const int by = s8 >> 3;
    const int row0 = by * 128;   // tokens
    const int col0 = bx * 128;   // codes

    const int rr = l >> 2;
    const int seg = (l & 3) * 8;
    const unsigned short* ga0 = Xbf + (size_t)(row0 + w * 32 + rr) * DIM + seg;
    const unsigned short* ga1 = ga0 + (size_t)16 * DIM;
    const unsigned short* gb0 = Ibf + (size_t)(col0 + w * 32 + rr) * DIM + seg;
    const unsigned short* gb1 = gb0 + (size_t)16 * DIM;
    unsigned short* la0 = As + (w * 32) * 32;
    unsigned short* la1 = As + (w * 32 + 16) * 32;
    unsigned short* lb0 = Bs + (w * 32) * 32;
    unsigned short* lb1 = Bs + (w * 32 + 16) * 32;

    const int wm = w & 1, wn = w >> 1;
    const int lr = l & 15;
    const int kq = (l >> 4) * 8;
    int aoff[4], boff[4];
    #pragma unroll
    for (int i = 0; i < 4; ++i) {
        aoff[i] = (wm * 64 + i * 16 + lr) * 32 + kq;
        boff[i] = (wn * 64 + i * 16 + lr) * 32 + kq;
    }

    f32x4 acc[4][4];
    #pragma unroll
    for (int i = 0; i < 4; ++i)
        #pragma unroll
        for (int j = 0; j < 4; ++j) acc[i][j] = (f32x4)0.f;

    for (int k0 = 0; k0 < DIM; k0 += 32) {
        gl_lds16(ga0, la0); gl_lds16(ga1, la1);
        gl_lds16(gb0, lb0); gl_lds16(gb1, lb1);
        ga0 += 32; ga1 += 32; gb0 += 32; gb1 += 32;
        __syncthreads();
        bf16x8 af[4], bfr[4];
        #pragma unroll
        for (int i = 0; i < 4; ++i) af[i] = *(const bf16x8*)(As + aoff[i]);
        #pragma unroll
        for (int i = 0; i < 4; ++i) bfr[i] = *(const bf16x8*)(Bs + boff[i]);
        #pragma unroll
        for (int i = 0; i < 4; ++i)
            #pragma unroll
            for (int j = 0; j < 4; ++j)
                acc[i][j] = __builtin_amdgcn_mfma_f32_16x16x32_bf16(
                    af[i], bfr[j], acc[i][j], 0, 0, 0);
        __syncthreads();
    }

    // scores -> S (aliased LDS; safe: all As/Bs reads drained by last barrier)
    const int lrow = (l >> 4) * 4;
    #pragma unroll
    for (int j = 0; j < 4; ++j) {
        const int cloc = wn * 64 + j * 16 + lr;
        const float nc = norms[col0 + cloc];
        #pragma unroll
        for (int i = 0; i < 4; ++i) {
            #pragma unroll
            for (int r = 0; r < 4; ++r) {
                float d = fmaf(-2.f, acc[i][j][r], nc);
                S[wm * 64 + i * 16 + lrow + r][cloc] =
                    (unsigned short)(ord32(d) >> 16);
            }
        }
    }
    __syncthreads();

    // 256-thread scan: 2 threads per token, 64 cols each, uint-paired reads
    {
        const int t = tid & 127, h = tid >> 7;
        unsigned t0 = ~0u, t1 = ~0u, t2 = ~0u, t3 = ~0u;
        const unsigned* srow = (const unsigned*)&S[t][h * 64];
        const int cb0 = col0 + h * 64;
        #pragma unroll
        for (int i = 0; i < 32; ++i) {
            const unsigned u = srow[i];
            const unsigned v0 = (u << 16) | (unsigned)(cb0 + 2 * i);
            const unsigned v1 = (u & 0xffff0000u) | (unsigned)(cb0 + 2 * i + 1);
            #pragma unroll
            for (int q = 0; q < 2; ++q) {
                const unsigned v = q ? v1 : v0;
                if (v < t3) {
                    if (v < t2) {
                        t3 = t2;
                        if (v < t1) {
                            t2 = t1;
                            if (v < t0) { t1 = t0; t0 = v; } else t1 = v;
                        } else t2 = v;
                    } else t3 = v;
                }
            }
        }
        *(uint4*)&red[(t * 2 + h) * 4] = make_uint4(t0, t1, t2, t3);
    }
    __syncthreads();
    // merge two sorted-4 lists: 4-smallest set = min(a_i, b_{3-i}) (bitonic halver)
    if (tid < 128) {
        const unsigned* a = &red[(tid * 2) * 4];
        const unsigned* b = &red[(tid * 2 + 1) * 4];
        uint4 o;
        o.x = min(a[0], b[3]); o.y = min(a[1], b[2]);
        o.z = min(a[2], b[1]); o.w = min(a[3], b[0]);
        *(uint4*)(cand + ((size_t)(row0 + tid) * 64 + bx) * 4) = o;
    }
}

// --------------- merge top-4 lists, exact fp32 rescore, gather, loss
__global__ __launch_bounds__(64)
void merge_kernel(const float* __restrict__ X, const float* __restrict__ Imp,
                  const float* __restrict__ norms, const unsigned* __restrict__ cand,
                  float* __restrict__ out, float* __restrict__ loss) {
    const int t = blockIdx.x;
    const int l = threadIdx.x;
    __shared__ int cnt;
    __shared__ unsigned short clist[64];
    if (l == 0) cnt = 0;

    const uint4 c4 = *(const uint4*)(cand + ((size_t)t * 64 + l) * 4);
    unsigned mn = min(min(c4.x, c4.y), min(c4.z, c4.w));
    #pragma unroll
    for (int o = 32; o > 0; o >>= 1)
        mn = min(mn, (unsigned)__shfl_xor((int)mn, o, 64));
    const float thresh = unord32(mn & 0xffff0000u) + 0.25f;  // coarse-err margin
    __syncthreads();

    unsigned vv[4] = {c4.x, c4.y, c4.z, c4.w};
    #pragma unroll
    for (int i = 0; i < 4; ++i) {
        if (unord32(vv[i] & 0xffff0000u) <= thresh) {
            int p = atomicAdd(&cnt, 1);
            if (p < 64) clist[p] = (unsigned short)(vv[i] & 0xffffu);
        }
    }
    __syncthreads();
    const int n = cnt < 64 ? cnt : 64;

    const float4* xp = (const float4*)(X + (size_t)t * DIM);
    const float4 xa = xp[l * 2], xb = xp[l * 2 + 1];
    unsigned long long best = ~0ull;
    for (int i = 0; i < n; ++i) {
        const int c = clist[i];
        const float4* ip = (const float4*)(Imp + (size_t)c * DIM);
        const float4 ia = ip[l * 2], ib = ip[l * 2 + 1];
        float s = xa.x * ia.x + xa.y * ia.y + xa.z * ia.z + xa.w * ia.w
                + xb.x * ib.x + xb.y * ib.y + xb.z * ib.z + xb.w * ib.w;
        #pragma unroll
        for (int o = 32; o > 0; o >>= 1) s += __shfl_xor(s, o, 64);
        const float d = fmaf(-2.f, s, norms[c]);
        const unsigned long long p = ((unsigned long long)ord32(d) << 32) | (unsigned)c;
        if (p < best) best = p;
    }
    const int bi = (int)(best & 0xffffffffu);

    const float4* qp = (const float4*)(Imp + (size_t)bi * DIM);
    float4* op = (float4*)(out + (size_t)t * DIM);
    float ls = 0.f;
    #pragma unroll
    for (int jj = 0; jj < 2; ++jj) {
        const int j = l + jj * 64;
        const float4 q = qp[j], xv = xp[j];
        op[j] = q;
        const float dx = xv.x - q.x, dy = xv.y - q.y, dz = xv.z - q.z, dw = xv.w - q.w;
        ls += dx * dx + dy * dy + dz * dz + dw * dw;
    }
    #pragma unroll
    for (int o = 32; o > 0; o >>= 1) ls += __shfl_xor(ls, o, 64);
    if (l == 0) {
        atomicAdd(loss, ls);
        out[IDX_OFF + t] = (float)bi;
    }
}

// ------------------------------------------------------------ finalize
__global__ void fin_kernel(const float* __restrict__ loss, float* __restrict__ out) {
    out[LOSS_OFF] = 1.25f * (*loss) / (float)QELEMS;
}

extern "C" void kernel_launch(void* const* d_in, const int* in_sizes, int n_in,
                              void* d_out, int out_size, void* d_ws, size_t ws_size,
                              hipStream_t stream) {
    const float* x  = (const float*)d_in[0];   // [4,4096,512]
    const float* cb = (const float*)d_in[1];   // [8192,512]
    const float* W  = (const float*)d_in[2];   // [512,512]
    float* out = (float*)d_out;
    char* ws = (char*)d_ws;

    float* imp = (float*)ws;
    float* norms = (float*)(ws + OFF_NORMS);
    unsigned short* xbf = (unsigned short*)(ws + OFF_XBF);
    unsigned short* impbf = (unsigned short*)(ws + OFF_IMPBF);
    unsigned* cand = (unsigned*)(ws + OFF_CAND);
    float* loss = (float*)(ws + OFF_LOSS);

    hipLaunchKernelGGL(init_kernel, dim3(NCODE / 256), dim3(256), 0, stream, loss, norms);
    hipLaunchKernelGGL(gemm_bt_kernel, dim3(DIM / BN, NCODE / BM), dim3(256), 0, stream,
                       cb, W, imp, impbf, norms);
    hipLaunchKernelGGL(cvt_kernel, dim3(NTOK * DIM / 4 / 256), dim3(256), 0, stream,
                       x, xbf, NTOK * DIM / 4);
    hipLaunchKernelGGL(coarse_kernel, dim3(NCODE / 128, NTOK / 128), dim3(256), 0, stream,
                       xbf, impbf, norms, cand);
    hipLaunchKernelGGL(merge_kernel, dim3(NTOK), dim3(64), 0, stream,
                       x, imp, norms, cand, out, loss);
    hipLaunchKernelGGL(fin_kernel, dim3(1), dim3(1), 0, stream, loss, out);
}

// Round 4
// 400.647 us; speedup vs baseline: 7.6757x; 1.4853x over previous
//
#include <hip/hip_runtime.h>
#include <stdint.h>

#define DIM 512
#define NCODE 8192
#define NTOK 16384                      // B*N = 4*4096
#define QELEMS (NTOK * DIM)             // 8388608
#define IDX_OFF QELEMS
#define LOSS_OFF (QELEMS + NTOK)

// ---------------- workspace layout (bytes) ----------------
// imp fp32[NCODE*DIM] @0 ; norms @OFF_NORMS ; xbf u16[NTOK*DIM] @OFF_XBF ;
// impbf u16[NCODE*DIM] @OFF_IMPBF ; cand u32[NTOK*64*4] @OFF_CAND
// lossp f32[NTOK] aliases OFF_XBF (xbf dead after coarse_kernel)
#define OFF_NORMS ((size_t)NCODE * DIM * 4)
#define OFF_XBF   (OFF_NORMS + (size_t)NCODE * 4)
#define OFF_IMPBF (OFF_XBF + (size_t)NTOK * DIM * 2)
#define OFF_CAND  (OFF_IMPBF + (size_t)NCODE * DIM * 2)

typedef short bf16x8 __attribute__((ext_vector_type(8)));
typedef float f32x4 __attribute__((ext_vector_type(4)));

__device__ inline unsigned ord32(float f) {
    unsigned u = __float_as_uint(f);
    return (u & 0x80000000u) ? ~u : (u | 0x80000000u);
}
__device__ inline float unord32(unsigned u) {
    u = (u & 0x80000000u) ? (u & 0x7fffffffu) : ~u;
    return __uint_as_float(u);
}
__device__ inline unsigned short f2bf(float f) {  // RTN bf16
    unsigned u = __float_as_uint(f);
    return (unsigned short)((u + 0x7fffu + ((u >> 16) & 1u)) >> 16);
}
__device__ inline void gl_lds16(const void* g, void* l) {
    __builtin_amdgcn_global_load_lds(
        (const __attribute__((address_space(1))) void*)g,
        (__attribute__((address_space(3))) void*)l, 16, 0, 0);
}

// ---------------------------------------------------------------- init
__global__ void init_kernel(float* __restrict__ norms) {
    int i = blockIdx.x * blockDim.x + threadIdx.x;
    if (i < NCODE) norms[i] = 0.f;
}

// ---------------- implicit = cb @ W^T (fp32) + fused norms + bf16 copy
constexpr int BM = 128, BN = 128, BK = 16, KP = BK + 1;
__global__ __launch_bounds__(256, 2)
void gemm_bt_kernel(const float* __restrict__ A, const float* __restrict__ B,
                    float* __restrict__ C, unsigned short* __restrict__ Cbf,
                    float* __restrict__ norms) {
    __shared__ float As[BM][KP];
    __shared__ float Bs[BN][KP];
    const int tid = threadIdx.x;
    const int tx = tid & 15;
    const int ty = tid >> 4;
    const int row0 = blockIdx.y * BM;
    const int col0 = blockIdx.x * BN;
    float acc[8][8] = {};
    for (int k0 = 0; k0 < DIM; k0 += BK) {
        #pragma unroll
        for (int s = tid; s < BM * (BK / 4); s += 256) {
            int r = s >> 2, c4 = (s & 3) << 2;
            const float4 v = *(const float4*)(A + (size_t)(row0 + r) * DIM + k0 + c4);
            As[r][c4] = v.x; As[r][c4 + 1] = v.y; As[r][c4 + 2] = v.z; As[r][c4 + 3] = v.w;
        }
        #pragma unroll
        for (int s = tid; s < BN * (BK / 4); s += 256) {
            int r = s >> 2, c4 = (s & 3) << 2;
            const float4 v = *(const float4*)(B + (size_t)(col0 + r) * DIM + k0 + c4);
            Bs[r][c4] = v.x; Bs[r][c4 + 1] = v.y; Bs[r][c4 + 2] = v.z; Bs[r][c4 + 3] = v.w;
        }
        __syncthreads();
        #pragma unroll
        for (int kk = 0; kk < BK; ++kk) {
            float a[8], b[8];
            #pragma unroll
            for (int i = 0; i < 8; ++i) a[i] = As[ty * 8 + i][kk];
            #pragma unroll
            for (int j = 0; j < 8; ++j) b[j] = Bs[tx + j * 16][kk];
            #pragma unroll
            for (int i = 0; i < 8; ++i)
                #pragma unroll
                for (int j = 0; j < 8; ++j)
                    acc[i][j] = fmaf(a[i], b[j], acc[i][j]);
        }
        __syncthreads();
    }
    #pragma unroll
    for (int i = 0; i < 8; ++i) {
        const int row = row0 + ty * 8 + i;
        float np = 0.f;
        #pragma unroll
        for (int j = 0; j < 8; ++j) {
            const int col = col0 + tx + j * 16;
            const float v = acc[i][j];
            C[(size_t)row * DIM + col] = v;
            Cbf[(size_t)row * DIM + col] = f2bf(v);
            np = fmaf(v, v, np);
        }
        #pragma unroll
        for (int m = 1; m < 16; m <<= 1) np += __shfl_xor(np, m, 64);
        if (tx == 0) atomicAdd(&norms[row], np);
    }
}

// -------------------------------------------------- fp32 -> bf16 convert (x)
__global__ void cvt_kernel(const float* __restrict__ src,
                           unsigned short* __restrict__ dst, int n4) {
    int i = blockIdx.x * blockDim.x + threadIdx.x;
    if (i >= n4) return;
    float4 v = ((const float4*)src)[i];
    ushort4 o;
    o.x = f2bf(v.x); o.y = f2bf(v.y); o.z = f2bf(v.z); o.w = f2bf(v.w);
    ((ushort4*)dst)[i] = o;
}

// ------------------------------- coarse bf16 MFMA scoring + per-block top-4
__global__ __launch_bounds__(256, 4)
void coarse_kernel(const unsigned short* __restrict__ Xbf,
                   const unsigned short* __restrict__ Ibf,
                   const float* __restrict__ norms,
                   unsigned* __restrict__ cand) {
    __shared__ __align__(16) unsigned char smem[33280 + 4096];
    unsigned short* As = (unsigned short*)smem;            // [128][32]
    unsigned short* Bs = As + 128 * 32;                    // [128][32]
    unsigned short (*S)[130] = (unsigned short (*)[130])smem;  // aliases As/Bs
    unsigned* red = (unsigned*)(smem + 33280);             // [128][8]

    const int tid = threadIdx.x;
    const int l = tid & 63;
    const int w = tid >> 6;

    const int id = blockIdx.y * 64 + blockIdx.x;
    const int xcd = id & 7;
    const int s8 = id >> 3;
    const int bx = xcd * 8 + (s8 & 7);
    const int by = s8 >> 3;
    const int row0 = by * 128;   // tokens
    const int col0 = bx * 128;   // codes

    const int rr = l >> 2;
    const int seg = (l & 3) * 8;
    const unsigned short* ga0 = Xbf + (size_t)(row0 + w * 32 + rr) * DIM + seg;
    const unsigned short* ga1 = ga0 + (size_t)16 * DIM;
    const unsigned short* gb0 = Ibf + (size_t)(col0 + w * 32 + rr) * DIM + seg;
    const unsigned short* gb1 = gb0 + (size_t)16 * DIM;
    unsigned short* la0 = As + (w * 32) * 32;
    unsigned short* la1 = As + (w * 32 + 16) * 32;
    unsigned short* lb0 = Bs + (w * 32) * 32;
    unsigned short* lb1 = Bs + (w * 32 + 16) * 32;

    const int wm = w & 1, wn = w >> 1;
    const int lr = l & 15;
    const int kq = (l >> 4) * 8;
    int aoff[4], boff[4];
    #pragma unroll
    for (int i = 0; i < 4; ++i) {
        aoff[i] = (wm * 64 + i * 16 + lr) * 32 + kq;
        boff[i] = (wn * 64 + i * 16 + lr) * 32 + kq;
    }

    f32x4 acc[4][4];
    #pragma unroll
    for (int i = 0; i < 4; ++i)
        #pragma unroll
        for (int j = 0; j < 4; ++j) acc[i][j] = (f32x4)0.f;

    for (int k0 = 0; k0 < DIM; k0 += 32) {
        gl_lds16(ga0, la0); gl_lds16(ga1, la1);
        gl_lds16(gb0, lb0); gl_lds16(gb1, lb1);
        ga0 += 32; ga1 += 32; gb0 += 32; gb1 += 32;
        __syncthreads();
        bf16x8 af[4], bfr[4];
        #pragma unroll
        for (int i = 0; i < 4; ++i) af[i] = *(const bf16x8*)(As + aoff[i]);
        #pragma unroll
        for (int i = 0; i < 4; ++i) bfr[i] = *(const bf16x8*)(Bs + boff[i]);
        #pragma unroll
        for (int i = 0; i < 4; ++i)
            #pragma unroll
            for (int j = 0; j < 4; ++j)
                acc[i][j] = __builtin_amdgcn_mfma_f32_16x16x32_bf16(
                    af[i], bfr[j], acc[i][j], 0, 0, 0);
        __syncthreads();
    }

    const int lrow = (l >> 4) * 4;
    #pragma unroll
    for (int j = 0; j < 4; ++j) {
        const int cloc = wn * 64 + j * 16 + lr;
        const float nc = norms[col0 + cloc];
        #pragma unroll
        for (int i = 0; i < 4; ++i) {
            #pragma unroll
            for (int r = 0; r < 4; ++r) {
                float d = fmaf(-2.f, acc[i][j][r], nc);
                S[wm * 64 + i * 16 + lrow + r][cloc] =
                    (unsigned short)(ord32(d) >> 16);
            }
        }
    }
    __syncthreads();

    {
        const int t = tid & 127, h = tid >> 7;
        unsigned t0 = ~0u, t1 = ~0u, t2 = ~0u, t3 = ~0u;
        const unsigned* srow = (const unsigned*)&S[t][h * 64];
        const int cb0 = col0 + h * 64;
        #pragma unroll
        for (int i = 0; i < 32; ++i) {
            const unsigned u = srow[i];
            const unsigned v0 = (u << 16) | (unsigned)(cb0 + 2 * i);
            const unsigned v1 = (u & 0xffff0000u) | (unsigned)(cb0 + 2 * i + 1);
            #pragma unroll
            for (int q = 0; q < 2; ++q) {
                const unsigned v = q ? v1 : v0;
                if (v < t3) {
                    if (v < t2) {
                        t3 = t2;
                        if (v < t1) {
                            t2 = t1;
                            if (v < t0) { t1 = t0; t0 = v; } else t1 = v;
                        } else t2 = v;
                    } else t3 = v;
                }
            }
        }
        *(uint4*)&red[(t * 2 + h) * 4] = make_uint4(t0, t1, t2, t3);
    }
    __syncthreads();
    if (tid < 128) {
        const unsigned* a = &red[(tid * 2) * 4];
        const unsigned* b = &red[(tid * 2 + 1) * 4];
        uint4 o;
        o.x = min(a[0], b[3]); o.y = min(a[1], b[2]);
        o.z = min(a[2], b[1]); o.w = min(a[3], b[0]);
        *(uint4*)(cand + ((size_t)(row0 + tid) * 64 + bx) * 4) = o;
    }
}

// --------------- merge: one wave per token, ballot-compacted rescore,
// gather + per-token loss partial (NO global atomics)
__global__ __launch_bounds__(256)
void merge_kernel(const float* __restrict__ X, const float* __restrict__ Imp,
                  const float* __restrict__ norms, const unsigned* __restrict__ cand,
                  float* __restrict__ out, float* __restrict__ lossp) {
    const int t = blockIdx.x * 4 + (threadIdx.x >> 6);
    const int l = threadIdx.x & 63;

    const uint4 c4 = *(const uint4*)(cand + ((size_t)t * 64 + l) * 4);
    unsigned mn = min(min(c4.x, c4.y), min(c4.z, c4.w));
    #pragma unroll
    for (int o = 32; o > 0; o >>= 1)
        mn = min(mn, (unsigned)__shfl_xor((int)mn, o, 64));
    const float thresh = unord32(mn & 0xffff0000u) + 0.25f;  // coarse-err margin

    const float4* xp = (const float4*)(X + (size_t)t * DIM);
    const float4 xa = xp[l * 2], xb = xp[l * 2 + 1];

    const unsigned vv[4] = {c4.x, c4.y, c4.z, c4.w};
    unsigned long long best = ~0ull;
    #pragma unroll
    for (int i = 0; i < 4; ++i) {
        const bool pass = unord32(vv[i] & 0xffff0000u) <= thresh;
        unsigned long long m = __ballot(pass);
        while (m) {
            const int src = __ffsll((unsigned long long)m) - 1;
            m &= m - 1;
            const int c = __shfl((int)(vv[i] & 0xffffu), src, 64);
            const float4* ip = (const float4*)(Imp + (size_t)c * DIM);
            const float4 ia = ip[l * 2], ib = ip[l * 2 + 1];
            float s = xa.x * ia.x + xa.y * ia.y + xa.z * ia.z + xa.w * ia.w
                    + xb.x * ib.x + xb.y * ib.y + xb.z * ib.z + xb.w * ib.w;
            #pragma unroll
            for (int o = 32; o > 0; o >>= 1) s += __shfl_xor(s, o, 64);
            const float d = fmaf(-2.f, s, norms[c]);
            const unsigned long long p =
                ((unsigned long long)ord32(d) << 32) | (unsigned)c;
            if (p < best) best = p;
        }
    }
    const int bi = (int)(best & 0xffffffffu);   // wave-uniform

    const float4* qp = (const float4*)(Imp + (size_t)bi * DIM);
    float4* op = (float4*)(out + (size_t)t * DIM);
    float ls = 0.f;
    #pragma unroll
    for (int jj = 0; jj < 2; ++jj) {
        const int j = l + jj * 64;
        const float4 q = qp[j], xv = xp[j];
        op[j] = q;
        const float dx = xv.x - q.x, dy = xv.y - q.y, dz = xv.z - q.z, dw = xv.w - q.w;
        ls += dx * dx + dy * dy + dz * dz + dw * dw;
    }
    #pragma unroll
    for (int o = 32; o > 0; o >>= 1) ls += __shfl_xor(ls, o, 64);
    if (l == 0) {
        lossp[t] = ls;
        out[IDX_OFF + t] = (float)bi;
    }
}

// ------------------------------------------- finalize: reduce lossp[NTOK]
__global__ __launch_bounds__(1024)
void fin_kernel(const float* __restrict__ lossp, float* __restrict__ out) {
    __shared__ float part[16];
    float s = 0.f;
    for (int i = threadIdx.x; i < NTOK; i += 1024) s += lossp[i];
    #pragma unroll
    for (int o = 32; o > 0; o >>= 1) s += __shfl_xor(s, o, 64);
    if ((threadIdx.x & 63) == 0) part[threadIdx.x >> 6] = s;
    __syncthreads();
    if (threadIdx.x == 0) {
        float tot = 0.f;
        #pragma unroll
        for (int i = 0; i < 16; ++i) tot += part[i];
        out[LOSS_OFF] = 1.25f * tot / (float)QELEMS;
    }
}

extern "C" void kernel_launch(void* const* d_in, const int* in_sizes, int n_in,
                              void* d_out, int out_size, void* d_ws, size_t ws_size,
                              hipStream_t stream) {
    const float* x  = (const float*)d_in[0];   // [4,4096,512]
    const float* cb = (const float*)d_in[1];   // [8192,512]
    const float* W  = (const float*)d_in[2];   // [512,512]
    float* out = (float*)d_out;
    char* ws = (char*)d_ws;

    float* imp = (float*)ws;
    float* norms = (float*)(ws + OFF_NORMS);
    unsigned short* xbf = (unsigned short*)(ws + OFF_XBF);
    unsigned short* impbf = (unsigned short*)(ws + OFF_IMPBF);
    unsigned* cand = (unsigned*)(ws + OFF_CAND);
    float* lossp = (float*)(ws + OFF_XBF);     // aliases xbf (dead after coarse)

    hipLaunchKernelGGL(init_kernel, dim3(NCODE / 256), dim3(256), 0, stream, norms);
    hipLaunchKernelGGL(gemm_bt_kernel, dim3(DIM / BN, NCODE / BM), dim3(256), 0, stream,
                       cb, W, imp, impbf, norms);
    hipLaunchKernelGGL(cvt_kernel, dim3(NTOK * DIM / 4 / 256), dim3(256), 0, stream,
                       x, xbf, NTOK * DIM / 4);
    hipLaunchKernelGGL(coarse_kernel, dim3(NCODE / 128, NTOK / 128), dim3(256), 0, stream,
                       xbf, impbf, norms, cand);
    hipLaunchKernelGGL(merge_kernel, dim3(NTOK / 4), dim3(256), 0, stream,
                       x, imp, norms, cand, out, lossp);
    hipLaunchKernelGGL(fin_kernel, dim3(1), dim3(1024), 0, stream, lossp, out);
}